// Round 8
// baseline (39.239 us; speedup 1.0000x reference)
//
#include <hip/hip_runtime.h>

#define NX 4096
#define NY 2048
#define EPS 1e-8f
#define ROWS 8          // rows per wave strip (4 packed row-pairs)
#define CPW 63          // output columns per block
#define INV_D 0.001f

typedef float f32x2 __attribute__((ext_vector_type(2)));

__device__ __forceinline__ int clampi(int i, int lo, int hi) {
    return i < lo ? lo : (i > hi ? hi : i);
}

// Scalar one-rcp WENO5 (odd fn face only).
__device__ __forceinline__ float weno5_s(float qm2, float qm1, float q0,
                                         float qp1, float qp2) {
    float f1 = fmaf(1.0f/3.0f, qm2, fmaf(-7.0f/6.0f, qm1, (11.0f/6.0f)*q0));
    float f2 = fmaf(-1.0f/6.0f, qm1, fmaf(5.0f/6.0f, q0, (1.0f/3.0f)*qp1));
    float f3 = fmaf(1.0f/3.0f, q0, fmaf(5.0f/6.0f, qp1, (-1.0f/6.0f)*qp2));
    const float k1 = 13.0f/12.0f, k2 = 0.25f;
    float d1 = qm2 - 2.0f*qm1 + q0,  e1 = qm2 - 4.0f*qm1 + 3.0f*q0;
    float d2 = qm1 - 2.0f*q0 + qp1,  e2 = qm1 - qp1;
    float d3 = q0 - 2.0f*qp1 + qp2,  e3 = 3.0f*q0 - 4.0f*qp1 + qp2;
    float b1 = fmaf(k1, d1*d1, k2*(e1*e1));
    float b2 = fmaf(k1, d2*d2, k2*(e2*e2));
    float b3 = fmaf(k1, d3*d3, k2*(e3*e3));
    float t1 = b1 + EPS, t2 = b2 + EPS, t3 = b3 + EPS;
    float p23 = t2*t3, p13 = t1*t3, p12 = t1*t2;
    float w1 = 0.1f*(p23*p23), w2 = 0.6f*(p13*p13), w3 = 0.3f*(p12*p12);
    float num = fmaf(w1, f1, fmaf(w2, f2, w3*f3));
    return num * __builtin_amdgcn_rcpf((w1 + w2) + w3);
}

// Packed (2-wide) one-rcp WENO5: two independent faces at once.
__device__ __forceinline__ f32x2 weno5_pk(f32x2 qm2, f32x2 qm1, f32x2 q0,
                                          f32x2 qp1, f32x2 qp2) {
    f32x2 f1 = (1.0f/3.0f)*qm2 - (7.0f/6.0f)*qm1 + (11.0f/6.0f)*q0;
    f32x2 f2 = (-1.0f/6.0f)*qm1 + (5.0f/6.0f)*q0 + (1.0f/3.0f)*qp1;
    f32x2 f3 = (1.0f/3.0f)*q0 + (5.0f/6.0f)*qp1 - (1.0f/6.0f)*qp2;
    f32x2 d1 = qm2 - 2.0f*qm1 + q0;
    f32x2 e1 = qm2 - 4.0f*qm1 + 3.0f*q0;
    f32x2 d2 = qm1 - 2.0f*q0 + qp1;
    f32x2 e2 = qm1 - qp1;
    f32x2 d3 = q0 - 2.0f*qp1 + qp2;
    f32x2 e3 = 3.0f*q0 - 4.0f*qp1 + qp2;
    const float k1 = 13.0f/12.0f, k2 = 0.25f;
    f32x2 b1 = k1*(d1*d1) + k2*(e1*e1);
    f32x2 b2 = k1*(d2*d2) + k2*(e2*e2);
    f32x2 b3 = k1*(d3*d3) + k2*(e3*e3);
    f32x2 t1 = b1 + EPS, t2 = b2 + EPS, t3 = b3 + EPS;
    f32x2 p23 = t2*t3, p13 = t1*t3, p12 = t1*t2;
    f32x2 w1 = 0.1f*(p23*p23);
    f32x2 w2 = 0.6f*(p13*p13);
    f32x2 w3 = 0.3f*(p12*p12);
    f32x2 num = w1*f1 + w2*f2 + w3*f3;
    f32x2 den = (w1 + w2) + w3;
    f32x2 rc;
    rc.x = __builtin_amdgcn_rcpf(den.x);
    rc.y = __builtin_amdgcn_rcpf(den.y);
    return num * rc;
}

// One wave strip: 8 rows x 63 output columns. Small batched col/v loads,
// fn faces as packed pairs (covers pair-0 prefetch latency), then 4
// independent row-pairs with explicit next-pair prefetch -> the scheduler
// pipelines loads of pair p+1 over compute of pair p at low VGPR pressure.
template <bool EDGE>
__device__ __forceinline__ void run_strip(const float* __restrict__ h,
                                          const float* __restrict__ u,
                                          const float* __restrict__ v,
                                          float* __restrict__ out,
                                          int x0, int y0w, int lane) {
    const int xf = x0 - 1 + lane;                       // x-face this lane owns
    const int xo = x0 + lane;                           // output column
    const int xc = EDGE ? (xo < NX ? xo : NX - 1) : xo; // column for fn path
    const int xq = EDGE ? clampi(xf, 0, NX - 1) : xf;   // column for u loads

    int xs[6];
    if (EDGE) {
#pragma unroll
        for (int k = 0; k < 6; ++k) xs[k] = clampi(xf - 2 + k, 0, NX - 1);
    }

    // ---- batched column loads: h col (14) + v faces (9)
    float w[ROWS + 6];
#pragma unroll
    for (int k = 0; k < ROWS + 6; ++k) {
        int yy = EDGE ? clampi(y0w - 3 + k, 0, NY - 1) : (y0w - 3 + k);
        w[k] = h[(size_t)yy * NX + xc];
    }
    float vv[ROWS + 1];
#pragma unroll
    for (int j = 0; j <= ROWS; ++j) {
        int fy = EDGE ? clampi(y0w - 1 + j, 0, NY - 1) : (y0w - 1 + j);
        vv[j] = v[(size_t)fy * NX + xc];
    }

    float st[4][2][6];   // per row-pair x-stencils (statically indexed)
    float uu[4][2];

    // prefetch pair 0 (latency covered by fn compute below)
#pragma unroll
    for (int i = 0; i < 2; ++i) {
        const float* hr = h + (size_t)(y0w + i) * NX;
        if (EDGE) {
#pragma unroll
            for (int k = 0; k < 6; ++k) st[0][i][k] = hr[xs[k]];
        } else {
#pragma unroll
            for (int k = 0; k < 6; ++k) st[0][i][k] = hr[xf - 2 + k];
        }
        uu[0][i] = u[(size_t)(y0w + i) * NX + xq];
    }

    // ---- fn faces: 4 packed pairs + 1 scalar (fn[j] = face at row y0w-1+j)
    float fn[ROWS + 1];
#pragma unroll
    for (int j = 0; j < ROWS; j += 2) {
        float v0 = vv[j], v1 = vv[j + 1];
        bool p0 = (v0 >= 0.0f), p1 = (v1 >= 0.0f);
        f32x2 a = { p0 ? w[j]   : w[j+5], p1 ? w[j+1] : w[j+6] };
        f32x2 b = { p0 ? w[j+1] : w[j+4], p1 ? w[j+2] : w[j+5] };
        f32x2 c = { p0 ? w[j+2] : w[j+3], p1 ? w[j+3] : w[j+4] };
        f32x2 d = { p0 ? w[j+3] : w[j+2], p1 ? w[j+4] : w[j+3] };
        f32x2 e = { p0 ? w[j+4] : w[j+1], p1 ? w[j+5] : w[j+2] };
        f32x2 q = weno5_pk(a, b, c, d, e);
        fn[j] = v0 * q.x;
        fn[j + 1] = v1 * q.y;
    }
    {
        float vl = vv[ROWS];
        bool vp = (vl >= 0.0f);
        fn[ROWS] = vl * weno5_s(vp ? w[ROWS]   : w[ROWS+5],
                                vp ? w[ROWS+1] : w[ROWS+4],
                                vp ? w[ROWS+2] : w[ROWS+3],
                                vp ? w[ROWS+3] : w[ROWS+2],
                                vp ? w[ROWS+4] : w[ROWS+1]);
    }

    // ---- row-pair loop: prefetch p+1, compute p (fe packed across 2 rows)
#pragma unroll
    for (int p = 0; p < 4; ++p) {
        if (p < 3) {
#pragma unroll
            for (int i = 0; i < 2; ++i) {
                int y = y0w + 2 * (p + 1) + i;
                const float* hr = h + (size_t)y * NX;
                if (EDGE) {
#pragma unroll
                    for (int k = 0; k < 6; ++k) st[p+1][i][k] = hr[xs[k]];
                } else {
#pragma unroll
                    for (int k = 0; k < 6; ++k) st[p+1][i][k] = hr[xf - 2 + k];
                }
                uu[p+1][i] = u[(size_t)y * NX + xq];
            }
        }

        float u0 = uu[p][0], u1 = uu[p][1];
        bool q0p = (u0 >= 0.0f), q1p = (u1 >= 0.0f);
        f32x2 a = { q0p ? st[p][0][0] : st[p][0][5], q1p ? st[p][1][0] : st[p][1][5] };
        f32x2 b = { q0p ? st[p][0][1] : st[p][0][4], q1p ? st[p][1][1] : st[p][1][4] };
        f32x2 c = { q0p ? st[p][0][2] : st[p][0][3], q1p ? st[p][1][2] : st[p][1][3] };
        f32x2 d = { q0p ? st[p][0][3] : st[p][0][2], q1p ? st[p][1][3] : st[p][1][2] };
        f32x2 e = { q0p ? st[p][0][4] : st[p][0][1], q1p ? st[p][1][4] : st[p][1][1] };
        f32x2 q = weno5_pk(a, b, c, d, e);
        float fe0 = u0 * q.x;             // face at column xo-1, row 2p
        float fe1 = u1 * q.y;             // row 2p+1
        float fe0r = __shfl_down(fe0, 1); // face at column xo
        float fe1r = __shfl_down(fe1, 1);

        int r0 = 2 * p;
        float val0 = ((fe0 - fe0r) + (fn[r0]     - fn[r0 + 1])) * INV_D;
        float val1 = ((fe1 - fe1r) + (fn[r0 + 1] - fn[r0 + 2])) * INV_D;

        int y0r = y0w + r0;
        if (EDGE) {
            if (xo < 2 || xo >= NX - 2 || y0r < 2 || y0r >= NY - 2) val0 = 0.0f;
            if (xo < 2 || xo >= NX - 2 || y0r + 1 < 2 || y0r + 1 >= NY - 2) val1 = 0.0f;
            if (lane < CPW && xo < NX) {
                __builtin_nontemporal_store(val0, out + (size_t)y0r * NX + xo);
                __builtin_nontemporal_store(val1, out + (size_t)(y0r + 1) * NX + xo);
            }
        } else {
            if (lane < CPW) {
                __builtin_nontemporal_store(val0, out + (size_t)y0r * NX + xo);
                __builtin_nontemporal_store(val1, out + (size_t)(y0r + 1) * NX + xo);
            }
        }
    }
}

__global__ __launch_bounds__(256) void adv_kernel(const float* __restrict__ h,
                                                  const float* __restrict__ u,
                                                  const float* __restrict__ v,
                                                  float* __restrict__ out) {
    const int lane = threadIdx.x & 63;
    const int wid  = threadIdx.x >> 6;
    const int x0 = blockIdx.x * CPW;
    const int y0w = (blockIdx.y * 4 + wid) * ROWS;

    const bool edge = (blockIdx.x == 0) || (blockIdx.x >= 64) ||
                      (blockIdx.y == 0) || (blockIdx.y == gridDim.y - 1);
    if (edge)
        run_strip<true>(h, u, v, out, x0, y0w, lane);
    else
        run_strip<false>(h, u, v, out, x0, y0w, lane);
}

extern "C" void kernel_launch(void* const* d_in, const int* in_sizes, int n_in,
                              void* d_out, int out_size, void* d_ws, size_t ws_size,
                              hipStream_t stream) {
    const float* h = (const float*)d_in[0];
    const float* u = (const float*)d_in[1];
    const float* v = (const float*)d_in[2];
    float* out = (float*)d_out;

    dim3 block(256, 1, 1);
    dim3 grid((NX + CPW - 1) / CPW, NY / (4 * ROWS), 1);  // 66 x 64
    adv_kernel<<<grid, block, 0, stream>>>(h, u, v, out);
}